// Round 7
// baseline (196.777 us; speedup 1.0000x reference)
//
#include <hip/hip_runtime.h>
#include <hip/hip_bf16.h>

// PhraseClassifier R7 (= R6 with epilogue store-loop fix: 8 iters, not 4 —
// each wave stores 32 rows x 128 cols = 512 8-byte tasks).
//   proj_gemm: 32Mx512N tiles (grid 1024, 4 blocks/CU via LDS union), bf16 MFMA,
//              fp8 output in pair-interleaved layout W[r] = [U[r] | V[r+1]].
//   span_eval: span reads TWO contiguous 1KB rows (b-1, e-1); LDS meta,
//              depth-3 load pipeline (12 loads in flight/lane); block partials.

typedef float f32x4 __attribute__((ext_vector_type(4)));
typedef float f32x2 __attribute__((ext_vector_type(2)));
typedef __bf16 bf16x8 __attribute__((ext_vector_type(8)));

__device__ __forceinline__ unsigned short f2bf(float f) {
  unsigned int u = __float_as_uint(f);
  u += 0x7fffu + ((u >> 16) & 1u);   // RNE
  return (unsigned short)(u >> 16);
}
__device__ __forceinline__ float bf2f(unsigned int lo16) {
  return __uint_as_float(lo16 << 16);
}

// ---------------- prep: W1 [1024][512] fp32 -> W1t [512][1024] bf16 ----------------
__global__ void w1_transpose(const float* __restrict__ W1, unsigned short* __restrict__ W1t) {
  __shared__ float tile[32][33];
  int k0 = blockIdx.x * 32, n0 = blockIdx.y * 32;
  int tx = threadIdx.x, ty = threadIdx.y;  // 32 x 8
#pragma unroll
  for (int r = 0; r < 4; ++r)
    tile[ty + r * 8][tx] = W1[(k0 + ty + r * 8) * 512 + n0 + tx];
  __syncthreads();
#pragma unroll
  for (int r = 0; r < 4; ++r)
    W1t[(n0 + ty + r * 8) * 1024 + k0 + tx] = f2bf(tile[tx][ty + r * 8]);
}

// ---------------- proj_gemm: 32M x 512N, K=512 (16 x BK=32) ----------------
// Grid (512, 2): x = M-tile (= one seq position, 32 batches), y = half
// (0: U, k 0..511; 1: V, k 512..1023). Wave w owns cols [w*128, w*128+128):
// acc 2m x 8n. LDS: Ab+Bb unioned with epilogue buffer -> ~35 KB -> 4 blocks/CU.
__global__ __launch_bounds__(256) void proj_gemm(
    const float* __restrict__ hidden,        // [16384][1024]
    const unsigned short* __restrict__ w1t,  // [512][1024] bf16
    unsigned char* __restrict__ Wq) {        // [16384][1024] fp8: [U[r] | V[r+32]]
  __shared__ __align__(16) char smem[35328];
  unsigned short* Ab = (unsigned short*)smem;            // 32 x 40 (+8 pad)
  unsigned short* Bb = (unsigned short*)(smem + 2560);   // 512 x 32, chunk-swizzled
  unsigned short* Eb = (unsigned short*)smem;            // overlay [4][32][136]

  const int t = threadIdx.x;
  const int lane = t & 63;
  const int w = t >> 6;
  const int r0 = blockIdx.x << 5;
  const int hk = blockIdx.y << 9;   // 0 (U) or 512 (V)

  f32x4 acc[2][8];
#pragma unroll
  for (int i = 0; i < 2; ++i)
#pragma unroll
    for (int j = 0; j < 8; ++j) acc[i][j] = (f32x4){0.f, 0.f, 0.f, 0.f};

  const int ar = t >> 3;            // A stage: row 0..31 (8 thr/row)
  const int akc = (t & 7) << 2;     // k offset 0,4,..,28
  const float* agp = hidden + (r0 + ar) * 1024 + hk + akc;

  // B: LDS chunk c of row n holds logical chunk c^((n>>1)&3) -> frag reads 2-way max
  int boff[8];
#pragma unroll
  for (int q = 0; q < 8; ++q) {
    int n = (w << 7) + (q << 4) + (lane >> 2);
    int sc = (lane & 3) ^ ((n >> 1) & 3);
    boff[q] = n * 1024 + hk + (sc << 3);
  }

  for (int it = 0; it < 16; ++it) {
    const int k0 = it << 5;
#pragma unroll
    for (int q = 0; q < 8; ++q) {
      const unsigned short* gp = w1t + boff[q] + k0;
      unsigned short* lp = &Bb[((w << 7) + (q << 4)) << 5];  // wave-uniform base
      __builtin_amdgcn_global_load_lds(
          (const __attribute__((address_space(1))) void*)gp,
          (__attribute__((address_space(3))) void*)lp, 16, 0, 0);
    }
    {
      float4 a = *(const float4*)(agp + k0);
      uint2 pk;
      pk.x = (unsigned)f2bf(a.x) | ((unsigned)f2bf(a.y) << 16);
      pk.y = (unsigned)f2bf(a.z) | ((unsigned)f2bf(a.w) << 16);
      *(uint2*)((char*)Ab + ar * 80 + akc * 2) = pk;
    }
    __syncthreads();

    bf16x8 af[2], bfr[8];
#pragma unroll
    for (int mt = 0; mt < 2; ++mt) {
      int row = (mt << 4) + (lane & 15);
      af[mt] = *(const bf16x8*)((const char*)Ab + row * 80 + ((lane >> 4) << 4));
    }
#pragma unroll
    for (int nt = 0; nt < 8; ++nt) {
      int n = (w << 7) + (nt << 4) + (lane & 15);
      int cs = (lane >> 4) ^ ((n >> 1) & 3);
      bfr[nt] = *(const bf16x8*)((const char*)Bb + n * 64 + (cs << 4));
    }
#pragma unroll
    for (int mt = 0; mt < 2; ++mt)
#pragma unroll
      for (int nt = 0; nt < 8; ++nt)
        acc[mt][nt] = __builtin_amdgcn_mfma_f32_16x16x32_bf16(af[mt], bfr[nt],
                                                              acc[mt][nt], 0, 0, 0);
    __syncthreads();
  }

  // Epilogue (overlays Ab/Bb; all frag reads drained at last barrier; Eb[w] is
  // wave-local so no further barrier needed). Repack row-major bf16, then
  // coalesced 8B/lane fp8 stores. C/D: col=lane&15, row=(lane>>4)*4+reg.
#pragma unroll
  for (int mt = 0; mt < 2; ++mt)
#pragma unroll
    for (int r = 0; r < 4; ++r) {
      int rr = (mt << 4) + ((lane >> 4) << 2) + r;   // 0..31
#pragma unroll
      for (int nt = 0; nt < 8; ++nt)
        Eb[((w << 5) + rr) * 136 + (nt << 4) + (lane & 15)] = f2bf(acc[mt][nt][r]);
    }
  // 32 rows x 128 cols per wave = 512 8-byte tasks = 8 iters x 64 lanes
#pragma unroll
  for (int i = 0; i < 8; ++i) {
    int task = (i << 6) + lane;
    int rr = task >> 4;                 // 0..31
    int ck = task & 15;                 // 8-col chunk within wave band
    uint4 v = *(const uint4*)&Eb[((w << 5) + rr) * 136 + (ck << 3)];
    float f0 = bf2f(v.x & 0xffff), f1 = bf2f(v.x >> 16);
    float f2 = bf2f(v.y & 0xffff), f3 = bf2f(v.y >> 16);
    float f4 = bf2f(v.z & 0xffff), f5 = bf2f(v.z >> 16);
    float f6 = bf2f(v.w & 0xffff), f7 = bf2f(v.w >> 16);
    uint2 o;
    o.x = __builtin_amdgcn_cvt_pk_fp8_f32(f0, f1, 0, false);
    o.x = __builtin_amdgcn_cvt_pk_fp8_f32(f2, f3, o.x, true);
    o.y = __builtin_amdgcn_cvt_pk_fp8_f32(f4, f5, 0, false);
    o.y = __builtin_amdgcn_cvt_pk_fp8_f32(f6, f7, o.y, true);
    int grow = r0 + rr;
    int col = (w << 7) + (ck << 3);
    if (hk == 0) {
      *(uint2*)(Wq + (grow << 10) + col) = o;             // U[r] -> row r, cols 0..511
    } else if (grow >= 32) {
      *(uint2*)(Wq + ((grow - 32) << 10) + 512 + col) = o; // V[r] -> row r-32 (seq-1)
    }
  }
}

// ---------------- span_eval: 1 span per half-wave, LDS meta, depth-3 pipeline ----
#define SPB 64
__global__ __launch_bounds__(256) void span_eval(
    const unsigned char* __restrict__ Wq,
    const int* __restrict__ bids, const int* __restrict__ begins,
    const int* __restrict__ ends, const int* __restrict__ flags,
    const float* __restrict__ weights,
    const float* __restrict__ b1, const float* __restrict__ w2,
    const float* __restrict__ b2, float* __restrict__ partials) {
  __shared__ int oB[SPB], oE[SPB], sfl[SPB];
  __shared__ float swt[SPB];
  __shared__ float red[4][3];
  const int t = threadIdx.x;
  const int lane = t & 63;
  const int w = t >> 6;
  const int h = lane >> 5;          // half-wave
  const int hl = lane & 31;
  const int sbase = blockIdx.x * SPB;

  if (t < SPB) {
    int s = sbase + t;
    int b = bids[s], bg = begins[s], en = ends[s];
    oB[t] = (((bg - 1) << 5) + b) << 10;   // row b-1: [U[b-1] | V[b]]
    oE[t] = (((en - 1) << 5) + b) << 10;   // row e-1: [U[e-1] | V[e]]
    sfl[t] = flags[s];
    swt[t] = weights[s];
  }
  __syncthreads();

  const int sp0 = ((w << 1) + h) << 3;   // my half-wave's first span (block-local)
  const int c0 = hl << 4;                // 16 u-cols per lane
  float b1v[16], w2v[16];
#pragma unroll
  for (int q = 0; q < 4; ++q) {
    float4 bv = *(const float4*)(b1 + c0 + (q << 2));
    float4 wv = *(const float4*)(w2 + c0 + (q << 2));
    b1v[(q << 2) + 0] = bv.x; b1v[(q << 2) + 1] = bv.y;
    b1v[(q << 2) + 2] = bv.z; b1v[(q << 2) + 3] = bv.w;
    w2v[(q << 2) + 0] = wv.x; w2v[(q << 2) + 1] = wv.y;
    w2v[(q << 2) + 2] = wv.z; w2v[(q << 2) + 3] = wv.w;
  }

  auto dec = [](unsigned int v, float* f) {
    f32x2 a = __builtin_amdgcn_cvt_pk_f32_fp8(v, false);
    f32x2 b = __builtin_amdgcn_cvt_pk_f32_fp8(v, true);
    f[0] = a[0]; f[1] = a[1]; f[2] = b[0]; f[3] = b[1];
  };

  uint4 BU[3], BV[3], EU[3], EV[3];
  auto ld = [&](int slot, int j) {
    int ob = oB[sp0 + j], oe = oE[sp0 + j];
    BU[slot] = *(const uint4*)(Wq + ob + c0);        // U[b-1] chunk
    BV[slot] = *(const uint4*)(Wq + ob + 512 + c0);  // V[b]   chunk
    EU[slot] = *(const uint4*)(Wq + oe + c0);        // U[e-1] chunk
    EV[slot] = *(const uint4*)(Wq + oe + 512 + c0);  // V[e]   chunk
  };
  ld(0, 0); ld(1, 1); ld(2, 2);

  float mylogit = 0.f;
#pragma unroll
  for (int j = 0; j < 8; ++j) {
    const int slot = j % 3;
    float buf[16], bvf[16], euf[16], evf[16];
    dec(BU[slot].x, buf); dec(BU[slot].y, buf + 4);
    dec(BU[slot].z, buf + 8); dec(BU[slot].w, buf + 12);
    dec(BV[slot].x, bvf); dec(BV[slot].y, bvf + 4);
    dec(BV[slot].z, bvf + 8); dec(BV[slot].w, bvf + 12);
    dec(EU[slot].x, euf); dec(EU[slot].y, euf + 4);
    dec(EU[slot].z, euf + 8); dec(EU[slot].w, euf + 12);
    dec(EV[slot].x, evf); dec(EV[slot].y, evf + 4);
    dec(EV[slot].z, evf + 8); dec(EV[slot].w, evf + 12);
    if (j + 3 < 8) ld(slot, j + 3);
    float sv = 0.f;
#pragma unroll
    for (int k = 0; k < 16; ++k) {
      float zp = euf[k] - buf[k] + bvf[k] - evf[k] + b1v[k];
      sv += fmaxf(zp, 0.f) * w2v[k];
    }
    sv += __shfl_xor(sv, 1);
    sv += __shfl_xor(sv, 2);
    sv += __shfl_xor(sv, 4);
    sv += __shfl_xor(sv, 8);
    sv += __shfl_xor(sv, 16);       // reduce within half-wave
    if (hl == j) mylogit = sv;      // lane h*32+j parks span sp0+j
  }

  // span w*16+l (l<16) parked at lane ((l&8)<<2)+(l&7)
  mylogit = __shfl(mylogit, ((lane & 8) << 2) + (lane & 7));

  float pos_t = 0.f, neg_t = 0.f, cnt_t = 0.f;
  if (lane < 16) {
    int sl = (w << 4) + lane;       // block-local span id
    float logit = mylogit + b2[0];
    float p = 1.f / (1.f + expf(-logit));
    p = fminf(fmaxf(p, 1e-7f), 1.f - 1e-7f);
    int fl = sfl[sl];
    float bce = (fl == 1) ? -logf(p) : -logf(1.f - p);
    float term = swt[sl] * bce;
    pos_t = (fl == 1) ? term : 0.f;
    neg_t = (fl == 1) ? 0.f : term;
    cnt_t = (fl == 1) ? 1.f : 0.f;
  }
#pragma unroll
  for (int off = 1; off < 64; off <<= 1) {
    pos_t += __shfl_xor(pos_t, off);
    neg_t += __shfl_xor(neg_t, off);
    cnt_t += __shfl_xor(cnt_t, off);
  }
  if (lane == 0) { red[w][0] = pos_t; red[w][1] = neg_t; red[w][2] = cnt_t; }
  __syncthreads();
  if (t == 0) {
    partials[(blockIdx.x << 2) + 0] = red[0][0] + red[1][0] + red[2][0] + red[3][0];
    partials[(blockIdx.x << 2) + 1] = red[0][1] + red[1][1] + red[2][1] + red[3][1];
    partials[(blockIdx.x << 2) + 2] = red[0][2] + red[1][2] + red[2][2] + red[3][2];
  }
}

// ---------------- finalize ----------------
__global__ void finalize(const float* __restrict__ parts, int nblk,
                         float* __restrict__ out, int nspans) {
  __shared__ float sp[4], sn[4], sc[4];
  float P = 0.f, Ng = 0.f, C = 0.f;
  for (int i = threadIdx.x; i < nblk; i += 256) {
    P += parts[(i << 2) + 0];
    Ng += parts[(i << 2) + 1];
    C += parts[(i << 2) + 2];
  }
#pragma unroll
  for (int off = 1; off < 64; off <<= 1) {
    P += __shfl_xor(P, off);
    Ng += __shfl_xor(Ng, off);
    C += __shfl_xor(C, off);
  }
  int w = threadIdx.x >> 6;
  if ((threadIdx.x & 63) == 0) { sp[w] = P; sn[w] = Ng; sc[w] = C; }
  __syncthreads();
  if (threadIdx.x == 0) {
    P = sp[0] + sp[1] + sp[2] + sp[3];
    Ng = sn[0] + sn[1] + sn[2] + sn[3];
    C = sc[0] + sc[1] + sc[2] + sc[3];
    float scale = 2.f * C / (float)nspans;
    out[0] = (P + scale * Ng) / (float)nspans;
  }
}

extern "C" void kernel_launch(void* const* d_in, const int* in_sizes, int n_in,
                              void* d_out, int out_size, void* d_ws, size_t ws_size,
                              hipStream_t stream) {
  const float* hidden = (const float*)d_in[0];
  const int* bids     = (const int*)d_in[1];
  const int* begins   = (const int*)d_in[2];
  const int* ends     = (const int*)d_in[3];
  const int* flags    = (const int*)d_in[4];
  const float* weights = (const float*)d_in[5];
  const float* W1 = (const float*)d_in[6];
  const float* b1 = (const float*)d_in[7];
  const float* W2 = (const float*)d_in[8];
  const float* b2 = (const float*)d_in[9];
  float* out = (float*)d_out;
  const int nspans = in_sizes[1];       // 131072
  const int nblk = nspans / SPB;        // 2048

  float* partials = (float*)d_ws;                                    // 32 KiB
  unsigned short* W1t = (unsigned short*)((char*)d_ws + (1 << 18));  // 1 MiB
  unsigned char* Wq = (unsigned char*)((char*)d_ws + (2 << 20));     // 16.8 MiB

  w1_transpose<<<dim3(32, 16), dim3(32, 8), 0, stream>>>(W1, W1t);
  proj_gemm<<<dim3(512, 2), 256, 0, stream>>>(hidden, W1t, Wq);
  span_eval<<<nblk, 256, 0, stream>>>(Wq, bids, begins, ends, flags, weights,
                                      b1, W2, b2, partials);
  finalize<<<1, 256, 0, stream>>>(partials, nblk, out, nspans);
}